// Round 1
// 544.499 us; speedup vs baseline: 1.0470x; 1.0470x over previous
//
#include <hip/hip_runtime.h>
#include <stdint.h>

// Problem constants (fixed by the reference).
#define L_EXPERTS 4
#define D_IN  2048
#define D_OUT 2048
#define B_TOK 16384

using f32x4  = __attribute__((ext_vector_type(4))) float;
using bf16x8 = __attribute__((ext_vector_type(8))) short;

__device__ __forceinline__ uint32_t f2bf(float f) {
    union { float f; uint32_t u; } v; v.f = f;
    uint32_t u = v.u;
    return (u + 0x7fffu + ((u >> 16) & 1u)) >> 16;   // RNE
}

__device__ __forceinline__ void gl_lds16(const void* g, void* l) {
    __builtin_amdgcn_global_load_lds(
        (const __attribute__((address_space(1))) void*)g,
        (__attribute__((address_space(3))) void*)l, 16, 0, 0);
}

// ---------------------------------------------------------------------------
// Sort stage A: per-block histograms (LDS atomics only). grid 64 x 256.
// ---------------------------------------------------------------------------
__global__ void hist_kernel(const int* __restrict__ idx, int* __restrict__ hist) {
    __shared__ int h[L_EXPERTS];
    if (threadIdx.x < L_EXPERTS) h[threadIdx.x] = 0;
    __syncthreads();
    const int e = idx[blockIdx.x * 256 + threadIdx.x];
    atomicAdd(&h[e], 1);
    __syncthreads();
    if (threadIdx.x < L_EXPERTS)
        hist[blockIdx.x * L_EXPERTS + threadIdx.x] = h[threadIdx.x];
}

// Sort stage B: totals + exclusive prefix -> meta[0..4] AND per-block bases
// bbase[b][e] = meta[e] + sum_{b'<b} hist[b'][e]. 1 block x 256.
// Replaces the global-atomic cursor (1024 same-cache-line atomics serialized
// at one L2 atomic unit -- the suspected hidden prep cost).
__global__ void prefix_kernel(const int* __restrict__ hist,
                              int* __restrict__ meta, int* __restrict__ bbase) {
    __shared__ int h[64][L_EXPERTS];
    __shared__ int tot[L_EXPERTS];
    const int b = threadIdx.x >> 2, e = threadIdx.x & 3;
    h[b][e] = hist[b * L_EXPERTS + e];
    __syncthreads();
    if (threadIdx.x < L_EXPERTS) {
        int s = 0;
        for (int bb = 0; bb < 64; ++bb) s += h[bb][threadIdx.x];
        tot[threadIdx.x] = s;
    }
    __syncthreads();
    if (threadIdx.x == 0) {
        int o = 0;
        for (int ee = 0; ee < L_EXPERTS; ++ee) { meta[ee] = o; o += tot[ee]; }
        meta[L_EXPERTS] = o;   // == B_TOK
    }
    if (threadIdx.x < L_EXPERTS) {
        const int ee = threadIdx.x;
        int base = 0;
        for (int e3 = 0; e3 < ee; ++e3) base += tot[e3];
        int run = base;
        for (int bb = 0; bb < 64; ++bb) {
            bbase[bb * L_EXPERTS + ee] = run;
            run += h[bb][ee];
        }
    }
}

// Sort stage C: fully deterministic scatter, zero global atomics.
// Per-wave ballot -> LDS wave counts -> tiny in-LDS scan -> position.
// grid 64 x 256.
__global__ void scatter_kernel(const int* __restrict__ idx,
                               const int* __restrict__ bbase,
                               int* __restrict__ perm) {
    __shared__ int wcnt[4][L_EXPERTS];
    __shared__ int wbase[4][L_EXPERTS];
    const int i = blockIdx.x * 256 + threadIdx.x;
    const int e = idx[i];
    const int w = threadIdx.x >> 6;
    const int lane = threadIdx.x & 63;
    const unsigned long long lt_mask = (1ull << lane) - 1ull;
    int my_off = 0;
    #pragma unroll
    for (int ee = 0; ee < L_EXPERTS; ++ee) {
        unsigned long long m = __ballot(e == ee);
        if (lane == 0) wcnt[w][ee] = __popcll(m);
        if (e == ee) my_off = __popcll(m & lt_mask);
    }
    __syncthreads();
    if (threadIdx.x < L_EXPERTS) {
        const int ee = threadIdx.x;
        int run = bbase[blockIdx.x * L_EXPERTS + ee];
        #pragma unroll
        for (int ww = 0; ww < 4; ++ww) { wbase[ww][ee] = run; run += wcnt[ww][ee]; }
    }
    __syncthreads();
    perm[wbase[w][e] + my_off] = i;
}

// ---------------------------------------------------------------------------
// Gather x rows in perm order, fp32 -> bf16. Grid-stride: 4096 blocks x 4 rows.
// ---------------------------------------------------------------------------
__global__ void gather_convert(const float* __restrict__ x,
                               const int* __restrict__ perm,
                               uint32_t* __restrict__ Ag) {
    const int j = threadIdx.x;                 // 256 threads, 8 floats each
    for (int p = blockIdx.x; p < B_TOK; p += gridDim.x) {
        const int t = perm[p];
        const float4* src = (const float4*)(x + (size_t)t * D_IN);
        uint4* dst = (uint4*)(Ag + (size_t)p * (D_IN / 2));
        float4 v0 = src[2 * j], v1 = src[2 * j + 1];
        uint4 o;
        o.x = f2bf(v0.x) | (f2bf(v0.y) << 16);
        o.y = f2bf(v0.z) | (f2bf(v0.w) << 16);
        o.z = f2bf(v1.x) | (f2bf(v1.y) << 16);
        o.w = f2bf(v1.z) | (f2bf(v1.w) << 16);
        dst[j] = o;
    }
}

// ---------------------------------------------------------------------------
// W [l][k][n] fp32 -> Wt [l][n][k] bf16. 64x64 tiles, float4 loads,
// 16 B packed stores. grid (32, 32, 4), block 256.
// ---------------------------------------------------------------------------
__global__ void wtrans(const float* __restrict__ W, ushort* __restrict__ Wt) {
    __shared__ float tile[64][65];
    const int l  = blockIdx.z;
    const int k0 = blockIdx.x * 64, n0 = blockIdx.y * 64;
    const float* Wl = W + (size_t)l * D_IN * D_OUT;
    ushort* Wtl = Wt + (size_t)l * D_IN * D_OUT;
    const int t = threadIdx.x;
    const int kr = t >> 4, nc = (t & 15) * 4;
    #pragma unroll
    for (int i = 0; i < 64; i += 16) {
        float4 v = *(const float4*)&Wl[(size_t)(k0 + kr + i) * D_OUT + n0 + nc];
        tile[kr + i][nc]     = v.x; tile[kr + i][nc + 1] = v.y;
        tile[kr + i][nc + 2] = v.z; tile[kr + i][nc + 3] = v.w;
    }
    __syncthreads();
    const int nr = t >> 3, kc = (t & 7) * 8;
    #pragma unroll
    for (int i = 0; i < 64; i += 32) {
        uint4 o;
        o.x = f2bf(tile[kc + 0][nr + i]) | (f2bf(tile[kc + 1][nr + i]) << 16);
        o.y = f2bf(tile[kc + 2][nr + i]) | (f2bf(tile[kc + 3][nr + i]) << 16);
        o.z = f2bf(tile[kc + 4][nr + i]) | (f2bf(tile[kc + 5][nr + i]) << 16);
        o.w = f2bf(tile[kc + 6][nr + i]) | (f2bf(tile[kc + 7][nr + i]) << 16);
        *(uint4*)&Wtl[(size_t)(n0 + nr + i) * D_IN + k0 + kc] = o;
    }
}

// ---------------------------------------------------------------------------
// Grouped GEMM. 256x256 tile, BK=32, 512 threads (8 waves, 2m x 4n),
// double-buffered LDS (2 x 32 KB), single barrier per K-iter (same verified
// structure as the 128^2 version -- only tile geometry changed).
// Halves bytes/FLOP vs 128^2: 32 KB staged per 4.2 MFLOP.
// Block mapping: nt = gid&7 -> XCD j keeps ONE 1 MB B-panel hot in its L2;
// A-panels stream through L3 (shared by all 8 XCDs).
// ---------------------------------------------------------------------------
__global__ __launch_bounds__(512, 2)
void gemm_grouped(const ushort* __restrict__ Ag, const ushort* __restrict__ Wt,
                  const float* __restrict__ bias, const int* __restrict__ meta,
                  const int* __restrict__ perm, float* __restrict__ out) {
    __shared__ __align__(16) ushort smem[2 * 32 * 512];   // 64 KB

    int off[L_EXPERTS + 1];
    #pragma unroll
    for (int i = 0; i <= L_EXPERTS; ++i) off[i] = meta[i];

    const int gid = blockIdx.x;
    const int nt = gid & 7;            // XCD id == n-tile: B-panel L2-resident
    const int mt = gid >> 3;

    int e = -1, lt = 0, t0 = 0;
    #pragma unroll
    for (int i = 0; i < L_EXPERTS; ++i) {
        int cnt = off[i + 1] - off[i];
        int tiles = (cnt + 255) >> 8;
        if (e < 0 && mt < t0 + tiles) { e = i; lt = mt - t0; }
        t0 += tiles;
    }
    if (e < 0) return;                      // padding blocks
    const int rowbase = off[e] + lt * 256;
    const int cnt_e   = off[e + 1] - off[e];
    const int n0      = nt * 256;

    const int tid  = threadIdx.x;
    const int lane = tid & 63;
    const int w    = tid >> 6;              // 0..7
    const int wm   = w & 1, wn = w >> 1;    // 2 m-halves x 4 n-quarters
    const int l15  = lane & 15, lq = lane >> 4;

    // Per-wave staging pointers: 32 chunks of 16(rows|cols) x 32 k = 1 KB each.
    const ushort* gp[4];
    #pragma unroll
    for (int q = 0; q < 4; ++q) {
        const int cidx = w * 4 + q;                 // wave-uniform chunk id
        if (cidx < 16) {                             // A chunk (256 rows)
            int row = rowbase + cidx * 16 + l15;
            if (row > B_TOK + 127) row = B_TOK + 127;   // clamp into Ag pad
            gp[q] = Ag + (size_t)row * D_IN + lq * 8;
        } else {                                     // B chunk (256 cols)
            int col = n0 + (cidx - 16) * 16 + l15;
            gp[q] = Wt + ((size_t)e * D_OUT + col) * D_IN + lq * 8;
        }
    }

    f32x4 acc[8][4] = {};
    const int NK = D_IN / 32;                        // 64 stages

    // Prefetch stage 0 into buffer 0.
    #pragma unroll
    for (int q = 0; q < 4; ++q)
        gl_lds16(gp[q], &smem[(w * 4 + q) * 512]);
    __syncthreads();

    for (int k = 0; k < NK; ++k) {
        if (k + 1 < NK) {                            // issue stage k+1
            const int nb = (k + 1) & 1;
            #pragma unroll
            for (int q = 0; q < 4; ++q)
                gl_lds16(gp[q] + (k + 1) * 32,
                         &smem[(nb * 32 + w * 4 + q) * 512]);
        }
        const ushort* base = &smem[(k & 1) * 32 * 512];
        bf16x8 af[8], bg[4];
        #pragma unroll
        for (int i = 0; i < 8; ++i)
            af[i] = *(const bf16x8*)&base[(wm * 8 + i) * 512 + lane * 8];
        #pragma unroll
        for (int j = 0; j < 4; ++j)
            bg[j] = *(const bf16x8*)&base[(16 + wn * 4 + j) * 512 + lane * 8];
        #pragma unroll
        for (int i = 0; i < 8; ++i)
            #pragma unroll
            for (int j = 0; j < 4; ++j)
                acc[i][j] = __builtin_amdgcn_mfma_f32_16x16x32_bf16(
                    af[i], bg[j], acc[i][j], 0, 0, 0);
        __syncthreads();                             // drains stage k+1 loads
    }

    // Epilogue: bias + scatter through perm. C layout: col=lane&15, row=lq*4+r.
    float bv[4];
    #pragma unroll
    for (int j = 0; j < 4; ++j)
        bv[j] = bias[(size_t)e * D_OUT + n0 + wn * 64 + j * 16 + l15];
    #pragma unroll
    for (int i = 0; i < 8; ++i) {
        #pragma unroll
        for (int r = 0; r < 4; ++r) {
            int lr = lt * 256 + wm * 128 + i * 16 + lq * 4 + r;
            if (lr < cnt_e) {
                int tok = perm[off[e] + lr];
                float* orow = out + (size_t)tok * D_OUT + n0 + wn * 64 + l15;
                #pragma unroll
                for (int j = 0; j < 4; ++j)
                    orow[j * 16] = acc[i][j][r] + bv[j];
            }
        }
    }
}

// ---------------------------------------------------------------------------
// Fallback (only if ws_size is too small): naive fp32, correct but slow.
// ---------------------------------------------------------------------------
__global__ void fallback_kernel(const float* __restrict__ x, const int* __restrict__ idx,
                                const float* __restrict__ W, const float* __restrict__ bias,
                                float* __restrict__ out) {
    __shared__ float xs[D_IN];
    const int t = blockIdx.x;
    const int e = idx[t];
    const float* xr = x + (size_t)t * D_IN;
    for (int k = threadIdx.x; k < D_IN; k += 256) xs[k] = xr[k];
    __syncthreads();
    const float* We = W + (size_t)e * D_IN * D_OUT;
    #pragma unroll 2
    for (int j = 0; j < D_OUT / 256; ++j) {
        int col = threadIdx.x + j * 256;
        float a = bias[(size_t)e * D_OUT + col];
        for (int k = 0; k < D_IN; ++k) a += xs[k] * We[(size_t)k * D_OUT + col];
        out[(size_t)t * D_OUT + col] = a;
    }
}

// ---------------------------------------------------------------------------
extern "C" void kernel_launch(void* const* d_in, const int* in_sizes, int n_in,
                              void* d_out, int out_size, void* d_ws, size_t ws_size,
                              hipStream_t stream) {
    const float* x   = (const float*)d_in[0];
    const int*   idx = (const int*)d_in[1];
    const float* W   = (const float*)d_in[2];
    const float* b   = (const float*)d_in[3];
    float* out = (float*)d_out;

    // ws layout: [meta 256B][perm 64KB][Ag (B+128)*2048 bf16][Wt 4*2048*2048 bf16]
    // hist (1 KB) + bbase (1 KB) live in the head of the Ag region: dead before
    // gather_convert overwrites Ag. NEED is identical to the previous version.
    const size_t META_OFF = 0;
    const size_t PERM_OFF = 256;
    const size_t AG_OFF   = PERM_OFF + (size_t)B_TOK * 4;
    const size_t AG_BYTES = (size_t)(B_TOK + 128) * D_IN * 2;
    const size_t WT_OFF   = AG_OFF + AG_BYTES;
    const size_t WT_BYTES = (size_t)L_EXPERTS * D_IN * D_OUT * 2;
    const size_t NEED     = WT_OFF + WT_BYTES;        // ~101.3 MB

    if (ws_size < NEED) {   // launch-invariant branch: graph-safe
        fallback_kernel<<<B_TOK, 256, 0, stream>>>(x, idx, W, b, out);
        return;
    }

    int*      meta   = (int*)((char*)d_ws + META_OFF);
    int*      perm   = (int*)((char*)d_ws + PERM_OFF);
    int*      hist   = (int*)((char*)d_ws + AG_OFF);          // transient
    int*      bbase  = (int*)((char*)d_ws + AG_OFF + 1024);   // transient
    uint32_t* Ag     = (uint32_t*)((char*)d_ws + AG_OFF);
    ushort*   Wt     = (ushort*)((char*)d_ws + WT_OFF);

    hist_kernel   <<<64, 256, 0, stream>>>(idx, hist);
    prefix_kernel <<<1, 256, 0, stream>>>(hist, meta, bbase);
    scatter_kernel<<<64, 256, 0, stream>>>(idx, bbase, perm);
    gather_convert<<<4096, 256, 0, stream>>>(x, perm, Ag);
    wtrans        <<<dim3(32, 32, L_EXPERTS), 256, 0, stream>>>(W, Wt);
    // m-tile capacity: sum_e ceil(cnt_e/256) <= 67; pad to 68 m-tiles x 8 n-tiles
    gemm_grouped  <<<68 * 8, 512, 0, stream>>>(
        (const ushort*)Ag, Wt, b, meta, perm, out);
}

// Round 2
// 497.920 us; speedup vs baseline: 1.1449x; 1.0935x over previous
//
#include <hip/hip_runtime.h>
#include <stdint.h>

// Problem constants (fixed by the reference).
#define L_EXPERTS 4
#define D_IN  2048
#define D_OUT 2048
#define B_TOK 16384

using f32x4  = __attribute__((ext_vector_type(4))) float;
using bf16x8 = __attribute__((ext_vector_type(8))) short;

__device__ __forceinline__ uint32_t f2bf(float f) {
    union { float f; uint32_t u; } v; v.f = f;
    uint32_t u = v.u;
    return (u + 0x7fffu + ((u >> 16) & 1u)) >> 16;   // RNE
}

__device__ __forceinline__ void gl_lds16(const void* g, void* l) {
    __builtin_amdgcn_global_load_lds(
        (const __attribute__((address_space(1))) void*)g,
        (__attribute__((address_space(3))) void*)l, 16, 0, 0);
}

// ---------------------------------------------------------------------------
// Sort stage A: per-block histograms (LDS atomics only). grid 64 x 256.
// ---------------------------------------------------------------------------
__global__ void hist_kernel(const int* __restrict__ idx, int* __restrict__ hist) {
    __shared__ int h[L_EXPERTS];
    if (threadIdx.x < L_EXPERTS) h[threadIdx.x] = 0;
    __syncthreads();
    const int e = idx[blockIdx.x * 256 + threadIdx.x];
    atomicAdd(&h[e], 1);
    __syncthreads();
    if (threadIdx.x < L_EXPERTS)
        hist[blockIdx.x * L_EXPERTS + threadIdx.x] = h[threadIdx.x];
}

// ---------------------------------------------------------------------------
// Sort stage B+C fused: each block derives totals / its own bases from hist
// (64x4 ints, L2-hot) and scatters deterministically. Zero global atomics.
// Block 0 also publishes meta. grid 64 x 256.
// ---------------------------------------------------------------------------
__global__ void scatter_fused(const int* __restrict__ idx,
                              const int* __restrict__ hist,
                              int* __restrict__ meta,
                              int* __restrict__ perm) {
    __shared__ int wcnt[4][L_EXPERTS];
    __shared__ int wbase[4][L_EXPERTS];
    __shared__ int tot[L_EXPERTS], pre[L_EXPERTS];
    const int i = blockIdx.x * 256 + threadIdx.x;
    const int e = idx[i];
    const int w = threadIdx.x >> 6;
    const int lane = threadIdx.x & 63;
    const unsigned long long lt = (1ull << lane) - 1ull;
    int my_off = 0;
    #pragma unroll
    for (int ee = 0; ee < L_EXPERTS; ++ee) {
        unsigned long long m = __ballot(e == ee);
        if (lane == 0) wcnt[w][ee] = __popcll(m);
        if (e == ee) my_off = __popcll(m & lt);
    }
    if (threadIdx.x < L_EXPERTS) {
        const int ee = threadIdx.x;
        int t = 0, p = 0;
        for (int bb = 0; bb < 64; ++bb) {
            int h = hist[bb * L_EXPERTS + ee];
            if (bb < (int)blockIdx.x) p += h;
            t += h;
        }
        tot[ee] = t; pre[ee] = p;
    }
    __syncthreads();
    if (threadIdx.x < L_EXPERTS) {
        const int ee = threadIdx.x;
        int base = 0;
        for (int e2 = 0; e2 < ee; ++e2) base += tot[e2];
        int run = base + pre[ee];
        #pragma unroll
        for (int ww = 0; ww < 4; ++ww) { wbase[ww][ee] = run; run += wcnt[ww][ee]; }
        if (blockIdx.x == 0) {
            meta[ee] = base;
            if (ee == L_EXPERTS - 1) meta[L_EXPERTS] = base + tot[ee];
        }
    }
    __syncthreads();
    perm[wbase[w][e] + my_off] = i;
}

// ---------------------------------------------------------------------------
// Fused prep: even blocks transpose+convert W (4096 tiles), odd blocks gather
// x rows in perm order to bf16 (grid-stride). Interleaved by parity so the two
// BW-bound phases overlap; one launch instead of two.
// grid 8192 x 256.
// ---------------------------------------------------------------------------
__global__ void prep_fused(const float* __restrict__ x, const int* __restrict__ perm,
                           uint32_t* __restrict__ Ag,
                           const float* __restrict__ W, ushort* __restrict__ Wt) {
    const int b = blockIdx.x;
    if ((b & 1) == 0) {
        // ---- wtrans tile (4096 tiles): W [l][k][n] fp32 -> Wt [l][n][k] bf16
        __shared__ float tile[64][65];
        const int tb = b >> 1;
        const int l  = tb >> 10;
        const int k0 = (tb & 31) * 64, n0 = ((tb >> 5) & 31) * 64;
        const float* Wl = W + (size_t)l * D_IN * D_OUT;
        ushort* Wtl = Wt + (size_t)l * D_IN * D_OUT;
        const int t = threadIdx.x;
        const int kr = t >> 4, nc = (t & 15) * 4;
        #pragma unroll
        for (int i = 0; i < 64; i += 16) {
            float4 v = *(const float4*)&Wl[(size_t)(k0 + kr + i) * D_OUT + n0 + nc];
            tile[kr + i][nc]     = v.x; tile[kr + i][nc + 1] = v.y;
            tile[kr + i][nc + 2] = v.z; tile[kr + i][nc + 3] = v.w;
        }
        __syncthreads();
        const int nr = t >> 3, kc = (t & 7) * 8;
        #pragma unroll
        for (int i = 0; i < 64; i += 32) {
            uint4 o;
            o.x = f2bf(tile[kc + 0][nr + i]) | (f2bf(tile[kc + 1][nr + i]) << 16);
            o.y = f2bf(tile[kc + 2][nr + i]) | (f2bf(tile[kc + 3][nr + i]) << 16);
            o.z = f2bf(tile[kc + 4][nr + i]) | (f2bf(tile[kc + 5][nr + i]) << 16);
            o.w = f2bf(tile[kc + 6][nr + i]) | (f2bf(tile[kc + 7][nr + i]) << 16);
            *(uint4*)&Wtl[(size_t)(n0 + nr + i) * D_IN + k0 + kc] = o;
        }
    } else {
        // ---- gather+convert (grid-stride over 16384 rows)
        const int j = threadIdx.x;                 // 256 threads, 8 floats each
        for (int p = b >> 1; p < B_TOK; p += 4096) {
            const int t = perm[p];
            const float4* src = (const float4*)(x + (size_t)t * D_IN);
            uint4* dst = (uint4*)(Ag + (size_t)p * (D_IN / 2));
            float4 v0 = src[2 * j], v1 = src[2 * j + 1];
            uint4 o;
            o.x = f2bf(v0.x) | (f2bf(v0.y) << 16);
            o.y = f2bf(v0.z) | (f2bf(v0.w) << 16);
            o.z = f2bf(v1.x) | (f2bf(v1.y) << 16);
            o.w = f2bf(v1.z) | (f2bf(v1.w) << 16);
            dst[j] = o;
        }
    }
}

// ---------------------------------------------------------------------------
// Grouped GEMM, counted-vmcnt pipeline (T3+T4+T5 adapted to gl_lds staging).
// 256x256 tile, BK=32, 512 threads (8 waves, 2m x 4n).
// LDS: ring of 3 x 32 KB K-tile buffers (96 KB). Prefetch distance 2 K-tiles.
// Per K-tile: issue stage(kt+2) FIRST, then ds_read + 32 MFMA (setprio'd),
// then s_waitcnt vmcnt(4) (kt+2's 4 loads stay in flight -- never drained to 0
// in the main loop) + ONE raw s_barrier + sched_barrier(0).
// Safety: vmcnt(4)+barrier at end of kt m => all waves' kt m+1 loads landed
// before any wave reads them; ring-of-3 => the buffer being written (kt+2)
// is never the buffer being read (kt m), with wave skew bounded by barriers.
// ---------------------------------------------------------------------------
__global__ __launch_bounds__(512, 2)
void gemm_grouped(const ushort* __restrict__ Ag, const ushort* __restrict__ Wt,
                  const float* __restrict__ bias, const int* __restrict__ meta,
                  const int* __restrict__ perm, float* __restrict__ out) {
    __shared__ __align__(16) ushort smem[3 * 16384];   // 96 KB: 3 K-tile bufs

    int off[L_EXPERTS + 1];
    #pragma unroll
    for (int i = 0; i <= L_EXPERTS; ++i) off[i] = meta[i];

    const int gid = blockIdx.x;
    const int nt = gid & 7;            // XCD id == n-tile: B-panel L2-resident
    const int mt = gid >> 3;

    int e = -1, lt = 0, t0 = 0;
    #pragma unroll
    for (int i = 0; i < L_EXPERTS; ++i) {
        int cnt = off[i + 1] - off[i];
        int tiles = (cnt + 255) >> 8;
        if (e < 0 && mt < t0 + tiles) { e = i; lt = mt - t0; }
        t0 += tiles;
    }
    if (e < 0) return;                      // padding blocks
    const int rowbase = off[e] + lt * 256;
    const int cnt_e   = off[e + 1] - off[e];
    const int n0      = nt * 256;

    const int tid  = threadIdx.x;
    const int lane = tid & 63;
    const int w    = tid >> 6;              // 0..7
    const int wm   = w & 1, wn = w >> 1;    // 2 m-halves x 4 n-quarters
    const int l15  = lane & 15, lq = lane >> 4;

    // Per-wave staging pointers: 32 chunks of 16(rows|cols) x 32 k = 1 KB each.
    // Chunk layout (lane*16B) == MFMA A/B fragment layout -> conflict-free reads.
    const ushort* gp[4];
    #pragma unroll
    for (int q = 0; q < 4; ++q) {
        const int cidx = w * 4 + q;                 // wave-uniform chunk id
        if (cidx < 16) {                             // A chunk (256 rows)
            int row = rowbase + cidx * 16 + l15;
            if (row > B_TOK + 127) row = B_TOK + 127;   // clamp into Ag pad
            gp[q] = Ag + (size_t)row * D_IN + lq * 8;
        } else {                                     // B chunk (256 cols)
            int col = n0 + (cidx - 16) * 16 + l15;
            gp[q] = Wt + ((size_t)e * D_OUT + col) * D_IN + lq * 8;
        }
    }

    f32x4 acc[8][4] = {};
    const int NKT = D_IN / 32;                       // 64 K-tiles

    auto STAGE = [&](int kt, ushort* buf) {
        #pragma unroll
        for (int q = 0; q < 4; ++q)
            gl_lds16(gp[q] + (size_t)kt * 32, &buf[(w * 4 + q) * 512]);
    };

    auto COMPUTE = [&](const ushort* base) {
        bf16x8 bg[4], af[4];
        #pragma unroll
        for (int j = 0; j < 4; ++j)
            bg[j] = *(const bf16x8*)&base[(16 + wn * 4 + j) * 512 + lane * 8];
        #pragma unroll
        for (int i = 0; i < 4; ++i)
            af[i] = *(const bf16x8*)&base[(wm * 8 + i) * 512 + lane * 8];
        __builtin_amdgcn_s_setprio(1);
        #pragma unroll
        for (int i = 0; i < 4; ++i)
            #pragma unroll
            for (int j = 0; j < 4; ++j)
                acc[i][j] = __builtin_amdgcn_mfma_f32_16x16x32_bf16(
                    af[i], bg[j], acc[i][j], 0, 0, 0);
        __builtin_amdgcn_s_setprio(0);
        #pragma unroll
        for (int i = 0; i < 4; ++i)
            af[i] = *(const bf16x8*)&base[(wm * 8 + 4 + i) * 512 + lane * 8];
        __builtin_amdgcn_s_setprio(1);
        #pragma unroll
        for (int i = 0; i < 4; ++i)
            #pragma unroll
            for (int j = 0; j < 4; ++j)
                acc[4 + i][j] = __builtin_amdgcn_mfma_f32_16x16x32_bf16(
                    af[i], bg[j], acc[4 + i][j], 0, 0, 0);
        __builtin_amdgcn_s_setprio(0);
    };

    ushort* b0 = smem;
    ushort* b1 = smem + 16384;
    ushort* b2 = smem + 32768;

    // Prologue: stage kt0,kt1; wait for kt0 (kt1's 4 loads stay in flight).
    STAGE(0, b0);
    STAGE(1, b1);
    asm volatile("s_waitcnt vmcnt(4)" ::: "memory");
    __builtin_amdgcn_s_barrier();
    __builtin_amdgcn_sched_barrier(0);

    ushort* pc = b0;   // compute buffer (kt m)
    ushort* pn = b1;   // landed-next    (kt m+1)
    ushort* ps = b2;   // stage target   (kt m+2)
    for (int m = 0; m < NKT - 2; ++m) {
        STAGE(m + 2, ps);                 // issue BEFORE compute (T3)
        COMPUTE(pc);
        asm volatile("s_waitcnt vmcnt(4)" ::: "memory");   // counted, never 0
        __builtin_amdgcn_s_barrier();
        __builtin_amdgcn_sched_barrier(0);
        ushort* t = pc; pc = pn; pn = ps; ps = t;
    }
    // Tail: kt NKT-2 already landed (loop invariant), kt NKT-1 in flight.
    COMPUTE(pc);
    asm volatile("s_waitcnt vmcnt(0)" ::: "memory");
    __builtin_amdgcn_s_barrier();
    __builtin_amdgcn_sched_barrier(0);
    COMPUTE(pn);

    // Epilogue: bias + scatter through perm. C layout: col=lane&15, row=lq*4+r.
    float bv[4];
    #pragma unroll
    for (int j = 0; j < 4; ++j)
        bv[j] = bias[(size_t)e * D_OUT + n0 + wn * 64 + j * 16 + l15];
    #pragma unroll
    for (int i = 0; i < 8; ++i) {
        #pragma unroll
        for (int r = 0; r < 4; ++r) {
            int lr = lt * 256 + wm * 128 + i * 16 + lq * 4 + r;
            if (lr < cnt_e) {
                int tok = perm[off[e] + lr];
                float* orow = out + (size_t)tok * D_OUT + n0 + wn * 64 + l15;
                #pragma unroll
                for (int j = 0; j < 4; ++j)
                    orow[j * 16] = acc[i][j][r] + bv[j];
            }
        }
    }
}

// ---------------------------------------------------------------------------
// Fallback (only if ws_size is too small): naive fp32, correct but slow.
// ---------------------------------------------------------------------------
__global__ void fallback_kernel(const float* __restrict__ x, const int* __restrict__ idx,
                                const float* __restrict__ W, const float* __restrict__ bias,
                                float* __restrict__ out) {
    __shared__ float xs[D_IN];
    const int t = blockIdx.x;
    const int e = idx[t];
    const float* xr = x + (size_t)t * D_IN;
    for (int k = threadIdx.x; k < D_IN; k += 256) xs[k] = xr[k];
    __syncthreads();
    const float* We = W + (size_t)e * D_IN * D_OUT;
    #pragma unroll 2
    for (int j = 0; j < D_OUT / 256; ++j) {
        int col = threadIdx.x + j * 256;
        float a = bias[(size_t)e * D_OUT + col];
        for (int k = 0; k < D_IN; ++k) a += xs[k] * We[(size_t)k * D_OUT + col];
        out[(size_t)t * D_OUT + col] = a;
    }
}

// ---------------------------------------------------------------------------
extern "C" void kernel_launch(void* const* d_in, const int* in_sizes, int n_in,
                              void* d_out, int out_size, void* d_ws, size_t ws_size,
                              hipStream_t stream) {
    const float* x   = (const float*)d_in[0];
    const int*   idx = (const int*)d_in[1];
    const float* W   = (const float*)d_in[2];
    const float* b   = (const float*)d_in[3];
    float* out = (float*)d_out;

    // ws layout: [meta 256B][perm 64KB][Ag (B+128)*2048 bf16][Wt 4*2048*2048 bf16]
    // hist (1 KB) lives in the head of the Ag region: dead before prep_fused's
    // gather overwrites Ag. NEED is identical to previous versions.
    const size_t META_OFF = 0;
    const size_t PERM_OFF = 256;
    const size_t AG_OFF   = PERM_OFF + (size_t)B_TOK * 4;
    const size_t AG_BYTES = (size_t)(B_TOK + 128) * D_IN * 2;
    const size_t WT_OFF   = AG_OFF + AG_BYTES;
    const size_t WT_BYTES = (size_t)L_EXPERTS * D_IN * D_OUT * 2;
    const size_t NEED     = WT_OFF + WT_BYTES;        // ~101.3 MB

    if (ws_size < NEED) {   // launch-invariant branch: graph-safe
        fallback_kernel<<<B_TOK, 256, 0, stream>>>(x, idx, W, b, out);
        return;
    }

    int*      meta   = (int*)((char*)d_ws + META_OFF);
    int*      perm   = (int*)((char*)d_ws + PERM_OFF);
    int*      hist   = (int*)((char*)d_ws + AG_OFF);          // transient
    uint32_t* Ag     = (uint32_t*)((char*)d_ws + AG_OFF);
    ushort*   Wt     = (ushort*)((char*)d_ws + WT_OFF);

    hist_kernel   <<<64, 256, 0, stream>>>(idx, hist);
    scatter_fused <<<64, 256, 0, stream>>>(idx, hist, meta, perm);
    prep_fused    <<<8192, 256, 0, stream>>>(x, perm, Ag, W, Wt);
    // m-tile capacity: sum_e ceil(cnt_e/256) <= 67; pad to 68 m-tiles x 8 n-tiles
    gemm_grouped  <<<68 * 8, 512, 0, stream>>>(
        (const ushort*)Ag, Wt, b, meta, perm, out);
}